// Round 1
// baseline (4058.581 us; speedup 1.0000x reference)
//
#include <hip/hip_runtime.h>

// PointNet++ forward (B=8, N=4096, D=2, F=5)
// sa1: FPS 4096->2048, r=0.2, MLP 7->32->64
// sa2: FPS 2048->512,  r=0.4, MLP 66->64->128
// sa3: MLP 130->128->256, global max
// head: MLP 256->256->1024
//
// Discrete selections (FPS argmax, top-64 neighbor sets) are reproduced
// bit-exactly vs XLA: distances use __fmul_rn/__fadd_rn (no FMA contraction),
// argmax = first max, top_k ties = lowest index first.

// ---------------------------------------------------------------- FPS
template<int N, int T>
__global__ __launch_bounds__(T) void fps_kernel(
    const float* __restrict__ pos,   // [B][N][2]
    float* __restrict__ posq,        // [B][M][2]
    int M) {
  constexpr int PPT = N / T;
  constexpr int NW  = T / 64;
  __shared__ float sx[N], sy[N];
  __shared__ float rv[2][NW];
  __shared__ int   ri[2][NW];
  const int b = blockIdx.x, t = threadIdx.x;
  const float* p = pos + (size_t)b * N * 2;
  float x[PPT], y[PPT], d[PPT];
#pragma unroll
  for (int k = 0; k < PPT; ++k) {
    int pt = t + k * T;
    float xx = p[pt * 2 + 0], yy = p[pt * 2 + 1];
    x[k] = xx; y[k] = yy; sx[pt] = xx; sy[pt] = yy;
    d[k] = 1e9f;
  }
  __syncthreads();
  float lx = sx[0], ly = sy[0];
  if (t == 0) { posq[(size_t)b * M * 2 + 0] = lx; posq[(size_t)b * M * 2 + 1] = ly; }
  for (int i = 1; i < M; ++i) {
    float bv = -1.0f; int bp = 0;
#pragma unroll
    for (int k = 0; k < PPT; ++k) {
      float dx = x[k] - lx, dy = y[k] - ly;
      float dd = __fadd_rn(__fmul_rn(dx, dx), __fmul_rn(dy, dy));  // exact: no fma
      float nd = fminf(d[k], dd);
      d[k] = nd;
      if (nd > bv) { bv = nd; bp = t + k * T; }   // ascending k -> first-max kept
    }
#pragma unroll
    for (int off = 1; off < 64; off <<= 1) {
      float ov = __shfl_xor(bv, off);
      int   op = __shfl_xor(bp, off);
      if (ov > bv || (ov == bv && op < bp)) { bv = ov; bp = op; }
    }
    const int par = i & 1;
    if ((t & 63) == 0) { rv[par][t >> 6] = bv; ri[par][t >> 6] = bp; }
    __syncthreads();
    float wv = rv[par][0]; int wi = ri[par][0];
#pragma unroll
    for (int j = 1; j < NW; ++j) {
      float v2 = rv[par][j]; int i2 = ri[par][j];
      if (v2 > wv || (v2 == wv && i2 < wi)) { wv = v2; wi = i2; }
    }
    lx = sx[wi]; ly = sy[wi];
    if (t == 0) {
      posq[((size_t)b * M + i) * 2 + 0] = lx;
      posq[((size_t)b * M + i) * 2 + 1] = ly;
    }
    // no 2nd barrier: rv/ri double-buffered by parity
  }
}

// ------------------------------------------------- radius top-64 neighbors
// One wave per query. Exact set of <=64 nearest in-radius points,
// matching lax.top_k(-d2) with lowest-index tie-break.
template<int CPL>   // candidate points per lane = NPTS/64
__global__ __launch_bounds__(256) void nbr_kernel(
    const float* __restrict__ pts,   // [B][NPTS][2]
    const float* __restrict__ posq,  // [total_q][2]
    int* __restrict__ nbr,           // [total_q][64], -1 = invalid
    int M, int NPTS, int total_q, float R2) {
  const int wid = blockIdx.x * 4 + (threadIdx.x >> 6);
  if (wid >= total_q) return;
  const int lane = threadIdx.x & 63;
  const int b = wid / M;
  const float qx = posq[(size_t)wid * 2 + 0], qy = posq[(size_t)wid * 2 + 1];
  const float* p = pts + (size_t)b * NPTS * 2;
  unsigned bits[CPL];
  int cnt = 0;
#pragma unroll
  for (int k = 0; k < CPL; ++k) {
    int pt = lane + (k << 6);
    float dx = p[pt * 2 + 0] - qx, dy = p[pt * 2 + 1] - qy;
    float dd = __fadd_rn(__fmul_rn(dx, dx), __fmul_rn(dy, dy));  // exact
    bool inr = (dd <= R2);
    bits[k] = inr ? __float_as_uint(dd) : 0xFFFFFFFFu;
    cnt += __popcll(__ballot(inr));
  }
  const unsigned long long below = (1ULL << lane) - 1ULL;
  if (cnt <= 64) {
    int base = 0;
#pragma unroll
    for (int k = 0; k < CPL; ++k) {
      bool s = (bits[k] != 0xFFFFFFFFu);
      unsigned long long m = __ballot(s);
      if (s) nbr[(size_t)wid * 64 + base + __popcll(m & below)] = lane + (k << 6);
      base += __popcll(m);
    }
    for (int j = base + lane; j < 64; j += 64) nbr[(size_t)wid * 64 + j] = -1;
  } else {
    // bisection on float bit pattern for exact 64th smallest d2
    unsigned lo = 0, hi = __float_as_uint(R2);
    while (lo < hi) {
      unsigned mid = lo + ((hi - lo) >> 1);
      int c = 0;
#pragma unroll
      for (int k = 0; k < CPL; ++k) c += __popcll(__ballot(bits[k] <= mid));
      if (c >= 64) hi = mid; else lo = mid + 1;
    }
    int cless = 0;
#pragma unroll
    for (int k = 0; k < CPL; ++k) cless += __popcll(__ballot(bits[k] < lo));
    const int need = 64 - cless;     // ties to take at cutoff, ascending index
    int base = 0, tiecnt = 0;
#pragma unroll
    for (int k = 0; k < CPL; ++k) {
      bool tie = (bits[k] == lo);
      unsigned long long tm = __ballot(tie);
      bool s = (bits[k] < lo) || (tie && (tiecnt + __popcll(tm & below)) < need);
      tiecnt += __popcll(tm);
      unsigned long long m = __ballot(s);
      if (s) nbr[(size_t)wid * 64 + base + __popcll(m & below)] = lane + (k << 6);
      base += __popcll(m);
    }
    // base == 64 exactly; no fill needed
  }
}

// ------------------------------------------------------------ PointConv
// Wave per query. Phase B: lane = neighbor, compute hidden (W1t broadcast
// from LDS). Phase C: transpose hidden into LDS. Phase D: lane = out channel,
// W2 column in VGPRs, max over neighbors is lane-local (no cross-lane reduce).
template<int CIN, int H, int COUT, int QPB, int NPTS, int HS, int W1P>
__global__ __launch_bounds__(64 * QPB) void conv_kernel(
    const float* __restrict__ x,     // [B][NPTS][CIN]
    const float* __restrict__ pts,   // [B][NPTS][2]
    const float* __restrict__ posq,  // [total_q][2]
    const int* __restrict__ nbr,     // [total_q][64]
    const float* __restrict__ W1, const float* __restrict__ b1,   // [CIN+2][H],[H]
    const float* __restrict__ W2, const float* __restrict__ b2,   // [H][COUT],[COUT]
    float* __restrict__ out,         // [total_q][COUT]
    int M) {
  constexpr int CI2 = CIN + 2;
  __shared__ float sW1t[H * W1P];    // transposed: [H][CI2 padded]
  __shared__ float sB1[H];
  __shared__ float sHH[QPB * 64 * HS];
  const int tid = threadIdx.x;
  for (int j = tid; j < CI2 * H; j += 64 * QPB) {
    int c = j / H, h = j - c * H;
    sW1t[h * W1P + c] = W1[j];
  }
  for (int j = tid; j < H; j += 64 * QPB) sB1[j] = b1[j];
  __syncthreads();
  const int wv = tid >> 6, lane = tid & 63;
  const int wid = blockIdx.x * QPB + wv;
  const int b = wid / M;
  // Phase A: gather neighbor features + relative position
  const int idx = nbr[(size_t)wid * 64 + lane];
  const unsigned long long vm = __ballot(idx >= 0);
  const int ii = (idx < 0) ? 0 : idx;
  float in[CI2];
  {
    const float* xp = x + ((size_t)b * NPTS + ii) * CIN;
#pragma unroll
    for (int c = 0; c < CIN; ++c) in[c] = xp[c];
    float qx = posq[(size_t)wid * 2 + 0], qy = posq[(size_t)wid * 2 + 1];
    const float* pp = pts + ((size_t)b * NPTS + ii) * 2;
    in[CIN] = pp[0] - qx;
    in[CIN + 1] = pp[1] - qy;
  }
  // Phase B+C: hidden layer + transpose to LDS (wave-local, no barrier needed)
  float* hbase = &sHH[wv * 64 * HS];
#pragma unroll
  for (int h = 0; h < H; h += 4) {
    float vv[4];
#pragma unroll
    for (int j = 0; j < 4; ++j) {
      float a = sB1[h + j];
#pragma unroll
      for (int c = 0; c < CI2; ++c) a = fmaf(in[c], sW1t[(h + j) * W1P + c], a);
      vv[j] = fmaxf(a, 0.0f);
    }
    *(float4*)&hbase[lane * HS + h] = make_float4(vv[0], vv[1], vv[2], vv[3]);
  }
  // Phase D: second layer + masked max over neighbors
#pragma unroll
  for (int half = 0; half < COUT / 64; ++half) {
    const int o = half * 64 + lane;
    float w2r[H];
#pragma unroll
    for (int h = 0; h < H; ++h) w2r[h] = W2[h * COUT + o];
    const float b2o = b2[o];
    float m = -1e30f;
    for (int n = 0; n < 64; ++n) {
      const float4* hp = (const float4*)&hbase[n * HS];
      float a = b2o;
#pragma unroll
      for (int j = 0; j < H / 4; ++j) {
        float4 hv = hp[j];
        a = fmaf(hv.x, w2r[4 * j + 0], a);
        a = fmaf(hv.y, w2r[4 * j + 1], a);
        a = fmaf(hv.z, w2r[4 * j + 2], a);
        a = fmaf(hv.w, w2r[4 * j + 3], a);
      }
      a = ((vm >> n) & 1ULL) ? a : -1e9f;   // masked like reference (-BIG)
      m = fmaxf(m, a);
    }
    out[(size_t)wid * COUT + o] = m;
  }
}

// ---------------------------------------------------- global MLP (layer a)
__global__ __launch_bounds__(256) void u_kernel(
    const float* __restrict__ h2,     // [4096][128]
    const float* __restrict__ posq2,  // [4096][2]
    const float* __restrict__ W3a, const float* __restrict__ b3a,
    float* __restrict__ u) {          // [4096][128]
  const int p = blockIdx.x * 2 + (threadIdx.x >> 7);
  const int h = threadIdx.x & 127;
  const float* hp = h2 + (size_t)p * 128;
  float a = b3a[h];
  for (int c = 0; c < 128; ++c) a = fmaf(hp[c], W3a[c * 128 + h], a);
  a = fmaf(posq2[(size_t)p * 2 + 0], W3a[128 * 128 + h], a);
  a = fmaf(posq2[(size_t)p * 2 + 1], W3a[129 * 128 + h], a);
  u[(size_t)p * 128 + h] = fmaxf(a, 0.0f);
}

// ---------------------------------- global MLP (layer b) + partial max-pool
__global__ __launch_bounds__(256) void g_kernel(
    const float* __restrict__ u,      // [4096][128]
    const float* __restrict__ W3b, const float* __restrict__ b3b,
    float* __restrict__ part) {       // [64][256]
  __shared__ float su[64 * 128];
  const int bb = blockIdx.x;          // chunk of 64 consecutive points
  const float* up = u + (size_t)bb * 64 * 128;
  for (int j = threadIdx.x; j < 64 * 128; j += 256) su[j] = up[j];
  __syncthreads();
  const int o = threadIdx.x;
  float w[128];
#pragma unroll
  for (int h = 0; h < 128; ++h) w[h] = W3b[h * 256 + o];
  float m = -1e30f;
  for (int p = 0; p < 64; ++p) {
    float a = b3b[o];
    const float4* sp = (const float4*)&su[p * 128];
#pragma unroll
    for (int j = 0; j < 32; ++j) {
      float4 v = sp[j];
      a = fmaf(v.x, w[4 * j + 0], a);
      a = fmaf(v.y, w[4 * j + 1], a);
      a = fmaf(v.z, w[4 * j + 2], a);
      a = fmaf(v.w, w[4 * j + 3], a);
    }
    m = fmaxf(m, a);
  }
  part[(size_t)bb * 256 + o] = m;
}

// ------------------------------------------------------------------ head
__global__ __launch_bounds__(256) void head_kernel(
    const float* __restrict__ part,   // [64][256] (8 chunks per batch)
    const float* __restrict__ W4a, const float* __restrict__ b4a,
    const float* __restrict__ W4b, const float* __restrict__ b4b,
    float* __restrict__ out) {        // [8][1024]
  __shared__ float g[256], h4[256];
  const int b = blockIdx.x, t = threadIdx.x;
  float m = part[(size_t)(b * 8 + 0) * 256 + t];
  for (int c = 1; c < 8; ++c) m = fmaxf(m, part[(size_t)(b * 8 + c) * 256 + t]);
  g[t] = m;
  __syncthreads();
  float a = b4a[t];
  for (int c = 0; c < 256; ++c) a = fmaf(g[c], W4a[c * 256 + t], a);
  h4[t] = fmaxf(a, 0.0f);
  __syncthreads();
  for (int jj = 0; jj < 4; ++jj) {
    int o = t + jj * 256;
    float a2 = b4b[o];
    for (int c = 0; c < 256; ++c) a2 = fmaf(h4[c], W4b[c * 1024 + o], a2);
    out[(size_t)b * 1024 + o] = a2;
  }
}

// ------------------------------------------------------------------ launch
extern "C" void kernel_launch(void* const* d_in, const int* in_sizes, int n_in,
                              void* d_out, int out_size, void* d_ws, size_t ws_size,
                              hipStream_t stream) {
  (void)in_sizes; (void)n_in; (void)out_size; (void)ws_size;
  const float* x   = (const float*)d_in[0];
  const float* pos = (const float*)d_in[1];
  const float* w1a = (const float*)d_in[2];  const float* b1a = (const float*)d_in[3];
  const float* w1b = (const float*)d_in[4];  const float* b1b = (const float*)d_in[5];
  const float* w2a = (const float*)d_in[6];  const float* b2a = (const float*)d_in[7];
  const float* w2b = (const float*)d_in[8];  const float* b2b = (const float*)d_in[9];
  const float* w3a = (const float*)d_in[10]; const float* b3a = (const float*)d_in[11];
  const float* w3b = (const float*)d_in[12]; const float* b3b = (const float*)d_in[13];
  const float* w4a = (const float*)d_in[14]; const float* b4a = (const float*)d_in[15];
  const float* w4b = (const float*)d_in[16]; const float* b4b = (const float*)d_in[17];
  float* outp = (float*)d_out;

  char* ws = (char*)d_ws;
  size_t off = 0;
  float* posq1 = (float*)(ws + off); off += (size_t)8 * 2048 * 2 * 4;   // 128 KB
  float* posq2 = (float*)(ws + off); off += (size_t)8 * 512 * 2 * 4;    //  32 KB
  int*   nbr1  = (int*)  (ws + off); off += (size_t)16384 * 64 * 4;     //   4 MB
  int*   nbr2  = (int*)  (ws + off); off += (size_t)4096 * 64 * 4;      //   1 MB
  float* h1    = (float*)(ws + off); off += (size_t)16384 * 64 * 4;     //   4 MB
  float* h2    = (float*)(ws + off); off += (size_t)4096 * 128 * 4;     //   2 MB
  float* u3    = (float*)(ws + off); off += (size_t)4096 * 128 * 4;     //   2 MB
  float* part  = (float*)(ws + off); off += (size_t)64 * 256 * 4;       //  64 KB

  fps_kernel<4096, 512><<<dim3(8), dim3(512), 0, stream>>>(pos, posq1, 2048);
  fps_kernel<2048, 512><<<dim3(8), dim3(512), 0, stream>>>(posq1, posq2, 512);
  nbr_kernel<64><<<dim3(4096), dim3(256), 0, stream>>>(pos, posq1, nbr1,
                                                       2048, 4096, 16384, 0.04f);
  conv_kernel<5, 32, 64, 4, 4096, 36, 8><<<dim3(4096), dim3(256), 0, stream>>>(
      x, pos, posq1, nbr1, w1a, b1a, w1b, b1b, h1, 2048);
  nbr_kernel<32><<<dim3(1024), dim3(256), 0, stream>>>(posq1, posq2, nbr2,
                                                       512, 2048, 4096, 0.16f);
  conv_kernel<64, 64, 128, 2, 2048, 68, 68><<<dim3(2048), dim3(128), 0, stream>>>(
      h1, posq1, posq2, nbr2, w2a, b2a, w2b, b2b, h2, 512);
  u_kernel<<<dim3(2048), dim3(256), 0, stream>>>(h2, posq2, w3a, b3a, u3);
  g_kernel<<<dim3(64), dim3(256), 0, stream>>>(u3, w3b, b3b, part);
  head_kernel<<<dim3(8), dim3(256), 0, stream>>>(part, w4a, b4a, w4b, b4b, outp);
}

// Round 2
// 1995.148 us; speedup vs baseline: 2.0342x; 2.0342x over previous
//
#include <hip/hip_runtime.h>

// PointNet++ forward (B=8, N=4096, D=2, F=5)
// sa1: FPS 4096->2048, r=0.2, MLP 7->32->64
// sa2: FPS 2048->512,  r=0.4, MLP 66->64->128
// sa3: MLP 130->128->256, global max
// head: MLP 256->256->1024
//
// Discrete selections (FPS argmax, top-64 neighbor sets) are reproduced
// bit-exactly vs XLA: distances use __fmul_rn/__fadd_rn (no FMA contraction),
// argmax = first max, top_k ties = lowest index first.

// ---------------------------------------------------------------- FPS
// Latency-optimized: per-round reduction via DPP (VALU pipe) instead of
// ds_bpermute shuffles. Lane->point mapping is CONTIGUOUS so that
// "first tied lane" == "smallest point index" for exact argmax tie-break.
template<int N, int T>
__global__ __launch_bounds__(T) void fps_kernel(
    const float* __restrict__ pos,   // [B][N][2]
    float* __restrict__ posq,        // [B][M][2]
    int M) {
  constexpr int PPT = N / T;         // points per thread (contiguous chunk)
  constexpr int NW  = T / 64;
  __shared__ float sx[N], sy[N];
  __shared__ unsigned long long sp[2][NW];
  const int b = blockIdx.x, t = threadIdx.x;
  const float* p = pos + (size_t)b * N * 2;
  float x[PPT], y[PPT], d[PPT];
  {
    const float4* p4 = (const float4*)(p + (size_t)t * PPT * 2);
#pragma unroll
    for (int q = 0; q < PPT / 2; ++q) {
      float4 v = p4[q];
      x[2 * q + 0] = v.x; y[2 * q + 0] = v.y;
      x[2 * q + 1] = v.z; y[2 * q + 1] = v.w;
    }
  }
#pragma unroll
  for (int k = 0; k < PPT; ++k) {
    int pt = t * PPT + k;
    sx[pt] = x[k]; sy[pt] = y[k];
    d[k] = 1e9f;
  }
  __syncthreads();
  float lx = sx[0], ly = sy[0];
  if (t == 0) { posq[(size_t)b * M * 2 + 0] = lx; posq[(size_t)b * M * 2 + 1] = ly; }

#define DPP_UMAX(u, ctrl)                                                      \
  do {                                                                         \
    unsigned _o = (unsigned)__builtin_amdgcn_update_dpp(0, (int)(u), (ctrl),   \
                                                        0xf, 0xf, true);       \
    (u) = ((u) > _o) ? (u) : _o;                                               \
  } while (0)

  for (int i = 1; i < M; ++i) {
    float bv = -1.0f; int bp = 0;
#pragma unroll
    for (int k = 0; k < PPT; ++k) {
      float dx = x[k] - lx, dy = y[k] - ly;
      float dd = __fadd_rn(__fmul_rn(dx, dx), __fmul_rn(dy, dy));  // exact: no fma
      float nd = fminf(d[k], dd);
      d[k] = nd;
      if (nd > bv) { bv = nd; bp = t * PPT + k; }  // ascending k -> first max
    }
    // wave-level max on float bits (nonneg => uint order == float order)
    const unsigned mybits = __float_as_uint(bv);
    unsigned u = mybits;
    DPP_UMAX(u, 0x111);  // row_shr:1
    DPP_UMAX(u, 0x112);  // row_shr:2
    DPP_UMAX(u, 0x114);  // row_shr:4
    DPP_UMAX(u, 0x118);  // row_shr:8   -> lane15 of each row has row max
    DPP_UMAX(u, 0x142);  // row_bcast:15 -> lane31/63 accumulate
    DPP_UMAX(u, 0x143);  // row_bcast:31 -> lane63 has wave max
    const unsigned wvb = (unsigned)__builtin_amdgcn_readlane((int)u, 63);
    // first tied lane (contiguous mapping => smallest point index)
    const unsigned long long tm = __ballot(mybits == wvb);
    const int fl = (int)__builtin_ctzll(tm);
    const int wbp = __builtin_amdgcn_readlane(bp, fl);

    const int par = i & 1;
    if ((t & 63) == 0)
      sp[par][t >> 6] = ((unsigned long long)wvb << 32) | (unsigned)(~wbp);
    __syncthreads();
    unsigned long long best = sp[par][0];
#pragma unroll
    for (int j = 1; j < NW; ++j) {
      unsigned long long v = sp[par][j];
      best = (v > best) ? v : best;   // tie: larger ~idx == smaller idx
    }
    const int wi = (int)(~(unsigned)best);
    lx = sx[wi]; ly = sy[wi];
    if (t == 0) {
      posq[((size_t)b * M + i) * 2 + 0] = lx;
      posq[((size_t)b * M + i) * 2 + 1] = ly;
    }
    // no 2nd barrier: sp double-buffered by parity
  }
#undef DPP_UMAX
}

// ------------------------------------------------- radius top-64 neighbors
// One wave per query. Exact set of <=64 nearest in-radius points,
// matching lax.top_k(-d2) with lowest-index tie-break.
template<int CPL>   // candidate points per lane = NPTS/64
__global__ __launch_bounds__(256) void nbr_kernel(
    const float* __restrict__ pts,   // [B][NPTS][2]
    const float* __restrict__ posq,  // [total_q][2]
    int* __restrict__ nbr,           // [total_q][64], -1 = invalid
    int M, int NPTS, int total_q, float R2) {
  const int wid = blockIdx.x * 4 + (threadIdx.x >> 6);
  if (wid >= total_q) return;
  const int lane = threadIdx.x & 63;
  const int b = wid / M;
  const float qx = posq[(size_t)wid * 2 + 0], qy = posq[(size_t)wid * 2 + 1];
  const float* p = pts + (size_t)b * NPTS * 2;
  unsigned bits[CPL];
  int cnt = 0;
#pragma unroll
  for (int k = 0; k < CPL; ++k) {
    int pt = lane + (k << 6);
    float dx = p[pt * 2 + 0] - qx, dy = p[pt * 2 + 1] - qy;
    float dd = __fadd_rn(__fmul_rn(dx, dx), __fmul_rn(dy, dy));  // exact
    bool inr = (dd <= R2);
    bits[k] = inr ? __float_as_uint(dd) : 0xFFFFFFFFu;
    cnt += __popcll(__ballot(inr));
  }
  const unsigned long long below = (1ULL << lane) - 1ULL;
  if (cnt <= 64) {
    int base = 0;
#pragma unroll
    for (int k = 0; k < CPL; ++k) {
      bool s = (bits[k] != 0xFFFFFFFFu);
      unsigned long long m = __ballot(s);
      if (s) nbr[(size_t)wid * 64 + base + __popcll(m & below)] = lane + (k << 6);
      base += __popcll(m);
    }
    for (int j = base + lane; j < 64; j += 64) nbr[(size_t)wid * 64 + j] = -1;
  } else {
    // bisection on float bit pattern for exact 64th smallest d2
    unsigned lo = 0, hi = __float_as_uint(R2);
    while (lo < hi) {
      unsigned mid = lo + ((hi - lo) >> 1);
      int c = 0;
#pragma unroll
      for (int k = 0; k < CPL; ++k) c += __popcll(__ballot(bits[k] <= mid));
      if (c >= 64) hi = mid; else lo = mid + 1;
    }
    int cless = 0;
#pragma unroll
    for (int k = 0; k < CPL; ++k) cless += __popcll(__ballot(bits[k] < lo));
    const int need = 64 - cless;     // ties to take at cutoff, ascending index
    int base = 0, tiecnt = 0;
#pragma unroll
    for (int k = 0; k < CPL; ++k) {
      bool tie = (bits[k] == lo);
      unsigned long long tm = __ballot(tie);
      bool s = (bits[k] < lo) || (tie && (tiecnt + __popcll(tm & below)) < need);
      tiecnt += __popcll(tm);
      unsigned long long m = __ballot(s);
      if (s) nbr[(size_t)wid * 64 + base + __popcll(m & below)] = lane + (k << 6);
      base += __popcll(m);
    }
    // base == 64 exactly; no fill needed
  }
}

// ------------------------------------------------------------ PointConv
// Wave per query. Phase B: lane = neighbor, compute hidden (W1t broadcast
// from LDS). Phase C: transpose hidden into LDS. Phase D: lane = out channel,
// W2 column in VGPRs, max over neighbors is lane-local (no cross-lane reduce).
template<int CIN, int H, int COUT, int QPB, int NPTS, int HS, int W1P>
__global__ __launch_bounds__(64 * QPB) void conv_kernel(
    const float* __restrict__ x,     // [B][NPTS][CIN]
    const float* __restrict__ pts,   // [B][NPTS][2]
    const float* __restrict__ posq,  // [total_q][2]
    const int* __restrict__ nbr,     // [total_q][64]
    const float* __restrict__ W1, const float* __restrict__ b1,   // [CIN+2][H],[H]
    const float* __restrict__ W2, const float* __restrict__ b2,   // [H][COUT],[COUT]
    float* __restrict__ out,         // [total_q][COUT]
    int M) {
  constexpr int CI2 = CIN + 2;
  __shared__ float sW1t[H * W1P];    // transposed: [H][CI2 padded]
  __shared__ float sB1[H];
  __shared__ float sHH[QPB * 64 * HS];
  const int tid = threadIdx.x;
  for (int j = tid; j < CI2 * H; j += 64 * QPB) {
    int c = j / H, h = j - c * H;
    sW1t[h * W1P + c] = W1[j];
  }
  for (int j = tid; j < H; j += 64 * QPB) sB1[j] = b1[j];
  __syncthreads();
  const int wv = tid >> 6, lane = tid & 63;
  const int wid = blockIdx.x * QPB + wv;
  const int b = wid / M;
  // Phase A: gather neighbor features + relative position
  const int idx = nbr[(size_t)wid * 64 + lane];
  const unsigned long long vm = __ballot(idx >= 0);
  const int ii = (idx < 0) ? 0 : idx;
  float in[CI2];
  {
    const float* xp = x + ((size_t)b * NPTS + ii) * CIN;
#pragma unroll
    for (int c = 0; c < CIN; ++c) in[c] = xp[c];
    float qx = posq[(size_t)wid * 2 + 0], qy = posq[(size_t)wid * 2 + 1];
    const float* pp = pts + ((size_t)b * NPTS + ii) * 2;
    in[CIN] = pp[0] - qx;
    in[CIN + 1] = pp[1] - qy;
  }
  // Phase B+C: hidden layer + transpose to LDS (wave-local, no barrier needed)
  float* hbase = &sHH[wv * 64 * HS];
#pragma unroll
  for (int h = 0; h < H; h += 4) {
    float vv[4];
#pragma unroll
    for (int j = 0; j < 4; ++j) {
      float a = sB1[h + j];
#pragma unroll
      for (int c = 0; c < CI2; ++c) a = fmaf(in[c], sW1t[(h + j) * W1P + c], a);
      vv[j] = fmaxf(a, 0.0f);
    }
    *(float4*)&hbase[lane * HS + h] = make_float4(vv[0], vv[1], vv[2], vv[3]);
  }
  // Phase D: second layer + masked max over neighbors
#pragma unroll
  for (int half = 0; half < COUT / 64; ++half) {
    const int o = half * 64 + lane;
    float w2r[H];
#pragma unroll
    for (int h = 0; h < H; ++h) w2r[h] = W2[h * COUT + o];
    const float b2o = b2[o];
    float m = -1e30f;
    for (int n = 0; n < 64; ++n) {
      const float4* hp = (const float4*)&hbase[n * HS];
      float a = b2o;
#pragma unroll
      for (int j = 0; j < H / 4; ++j) {
        float4 hv = hp[j];
        a = fmaf(hv.x, w2r[4 * j + 0], a);
        a = fmaf(hv.y, w2r[4 * j + 1], a);
        a = fmaf(hv.z, w2r[4 * j + 2], a);
        a = fmaf(hv.w, w2r[4 * j + 3], a);
      }
      a = ((vm >> n) & 1ULL) ? a : -1e9f;   // masked like reference (-BIG)
      m = fmaxf(m, a);
    }
    out[(size_t)wid * COUT + o] = m;
  }
}

// ---------------------------------------------------- global MLP (layer a)
__global__ __launch_bounds__(256) void u_kernel(
    const float* __restrict__ h2,     // [4096][128]
    const float* __restrict__ posq2,  // [4096][2]
    const float* __restrict__ W3a, const float* __restrict__ b3a,
    float* __restrict__ u) {          // [4096][128]
  const int p = blockIdx.x * 2 + (threadIdx.x >> 7);
  const int h = threadIdx.x & 127;
  const float* hp = h2 + (size_t)p * 128;
  float a = b3a[h];
  for (int c = 0; c < 128; ++c) a = fmaf(hp[c], W3a[c * 128 + h], a);
  a = fmaf(posq2[(size_t)p * 2 + 0], W3a[128 * 128 + h], a);
  a = fmaf(posq2[(size_t)p * 2 + 1], W3a[129 * 128 + h], a);
  u[(size_t)p * 128 + h] = fmaxf(a, 0.0f);
}

// ---------------------------------- global MLP (layer b) + partial max-pool
__global__ __launch_bounds__(256) void g_kernel(
    const float* __restrict__ u,      // [4096][128]
    const float* __restrict__ W3b, const float* __restrict__ b3b,
    float* __restrict__ part) {       // [64][256]
  __shared__ float su[64 * 128];
  const int bb = blockIdx.x;          // chunk of 64 consecutive points
  const float* up = u + (size_t)bb * 64 * 128;
  for (int j = threadIdx.x; j < 64 * 128; j += 256) su[j] = up[j];
  __syncthreads();
  const int o = threadIdx.x;
  float w[128];
#pragma unroll
  for (int h = 0; h < 128; ++h) w[h] = W3b[h * 256 + o];
  float m = -1e30f;
  for (int p = 0; p < 64; ++p) {
    float a = b3b[o];
    const float4* sp = (const float4*)&su[p * 128];
#pragma unroll
    for (int j = 0; j < 32; ++j) {
      float4 v = sp[j];
      a = fmaf(v.x, w[4 * j + 0], a);
      a = fmaf(v.y, w[4 * j + 1], a);
      a = fmaf(v.z, w[4 * j + 2], a);
      a = fmaf(v.w, w[4 * j + 3], a);
    }
    m = fmaxf(m, a);
  }
  part[(size_t)bb * 256 + o] = m;
}

// ------------------------------------------------------------------ head
__global__ __launch_bounds__(256) void head_kernel(
    const float* __restrict__ part,   // [64][256] (8 chunks per batch)
    const float* __restrict__ W4a, const float* __restrict__ b4a,
    const float* __restrict__ W4b, const float* __restrict__ b4b,
    float* __restrict__ out) {        // [8][1024]
  __shared__ float g[256], h4[256];
  const int b = blockIdx.x, t = threadIdx.x;
  float m = part[(size_t)(b * 8 + 0) * 256 + t];
  for (int c = 1; c < 8; ++c) m = fmaxf(m, part[(size_t)(b * 8 + c) * 256 + t]);
  g[t] = m;
  __syncthreads();
  float a = b4a[t];
  for (int c = 0; c < 256; ++c) a = fmaf(g[c], W4a[c * 256 + t], a);
  h4[t] = fmaxf(a, 0.0f);
  __syncthreads();
  for (int jj = 0; jj < 4; ++jj) {
    int o = t + jj * 256;
    float a2 = b4b[o];
    for (int c = 0; c < 256; ++c) a2 = fmaf(h4[c], W4b[c * 1024 + o], a2);
    out[(size_t)b * 1024 + o] = a2;
  }
}

// ------------------------------------------------------------------ launch
extern "C" void kernel_launch(void* const* d_in, const int* in_sizes, int n_in,
                              void* d_out, int out_size, void* d_ws, size_t ws_size,
                              hipStream_t stream) {
  (void)in_sizes; (void)n_in; (void)out_size; (void)ws_size;
  const float* x   = (const float*)d_in[0];
  const float* pos = (const float*)d_in[1];
  const float* w1a = (const float*)d_in[2];  const float* b1a = (const float*)d_in[3];
  const float* w1b = (const float*)d_in[4];  const float* b1b = (const float*)d_in[5];
  const float* w2a = (const float*)d_in[6];  const float* b2a = (const float*)d_in[7];
  const float* w2b = (const float*)d_in[8];  const float* b2b = (const float*)d_in[9];
  const float* w3a = (const float*)d_in[10]; const float* b3a = (const float*)d_in[11];
  const float* w3b = (const float*)d_in[12]; const float* b3b = (const float*)d_in[13];
  const float* w4a = (const float*)d_in[14]; const float* b4a = (const float*)d_in[15];
  const float* w4b = (const float*)d_in[16]; const float* b4b = (const float*)d_in[17];
  float* outp = (float*)d_out;

  char* ws = (char*)d_ws;
  size_t off = 0;
  float* posq1 = (float*)(ws + off); off += (size_t)8 * 2048 * 2 * 4;   // 128 KB
  float* posq2 = (float*)(ws + off); off += (size_t)8 * 512 * 2 * 4;    //  32 KB
  int*   nbr1  = (int*)  (ws + off); off += (size_t)16384 * 64 * 4;     //   4 MB
  int*   nbr2  = (int*)  (ws + off); off += (size_t)4096 * 64 * 4;      //   1 MB
  float* h1    = (float*)(ws + off); off += (size_t)16384 * 64 * 4;     //   4 MB
  float* h2    = (float*)(ws + off); off += (size_t)4096 * 128 * 4;     //   2 MB
  float* u3    = (float*)(ws + off); off += (size_t)4096 * 128 * 4;     //   2 MB
  float* part  = (float*)(ws + off); off += (size_t)64 * 256 * 4;       //  64 KB

  fps_kernel<4096, 512><<<dim3(8), dim3(512), 0, stream>>>(pos, posq1, 2048);
  fps_kernel<2048, 512><<<dim3(8), dim3(512), 0, stream>>>(posq1, posq2, 512);
  nbr_kernel<64><<<dim3(4096), dim3(256), 0, stream>>>(pos, posq1, nbr1,
                                                       2048, 4096, 16384, 0.04f);
  conv_kernel<5, 32, 64, 4, 4096, 36, 8><<<dim3(4096), dim3(256), 0, stream>>>(
      x, pos, posq1, nbr1, w1a, b1a, w1b, b1b, h1, 2048);
  nbr_kernel<32><<<dim3(1024), dim3(256), 0, stream>>>(posq1, posq2, nbr2,
                                                       512, 2048, 4096, 0.16f);
  conv_kernel<64, 64, 128, 2, 2048, 68, 68><<<dim3(2048), dim3(128), 0, stream>>>(
      h1, posq1, posq2, nbr2, w2a, b2a, w2b, b2b, h2, 512);
  u_kernel<<<dim3(2048), dim3(256), 0, stream>>>(h2, posq2, w3a, b3a, u3);
  g_kernel<<<dim3(64), dim3(256), 0, stream>>>(u3, w3b, b3b, part);
  head_kernel<<<dim3(8), dim3(256), 0, stream>>>(part, w4a, b4a, w4b, b4b, outp);
}